// Round 4
// baseline (193.450 us; speedup 1.0000x reference)
//
#include <hip/hip_runtime.h>

#define BB 16
#define LL 2048
#define DD 768
#define KK 32
#define TILE 16
#define NEGI -1e30f

// ---------------- Kernel 1: per-token scores + weight-buffer init ----------------
// One wave per token, fully coalesced: lane reads float4s {lane, lane+64, lane+128}
// of the 192-float4 row (each VMEM instruction = contiguous 1 KB).
__global__ __launch_bounds__(256) void scores_k(
    const float* __restrict__ th,
    const float* __restrict__ attn,
    const float* __restrict__ wp,
    const float* __restrict__ bp,
    float* __restrict__ scores,
    float* __restrict__ wbuf,
    int* __restrict__ idbuf) {
  const int lane = threadIdx.x & 63;
  const int wave = threadIdx.x >> 6;
  const int token = (blockIdx.x << 2) + wave;  // < B*L = 32768

  const float4* row = (const float4*)(th + (size_t)token * DD);
  const float4* wr  = (const float4*)wp;

  float4 a0 = row[lane], a1 = row[lane + 64], a2 = row[lane + 128];
  float4 w0 = wr[lane],  w1 = wr[lane + 64],  w2 = wr[lane + 128];

  float acc = 0.f;
  acc = fmaf(a0.x, w0.x, acc); acc = fmaf(a0.y, w0.y, acc);
  acc = fmaf(a0.z, w0.z, acc); acc = fmaf(a0.w, w0.w, acc);
  acc = fmaf(a1.x, w1.x, acc); acc = fmaf(a1.y, w1.y, acc);
  acc = fmaf(a1.z, w1.z, acc); acc = fmaf(a1.w, w1.w, acc);
  acc = fmaf(a2.x, w2.x, acc); acc = fmaf(a2.y, w2.y, acc);
  acc = fmaf(a2.z, w2.z, acc); acc = fmaf(a2.w, w2.w, acc);

  #pragma unroll
  for (int o = 32; o > 0; o >>= 1) acc += __shfl_xor(acc, o, 64);

  if (lane == 0) {
    float s = acc + bp[0];
    scores[token] = (attn[token] >= 0.5f) ? s : NEGI;
    wbuf[token]   = 0.f;   // gap/default weight (spanprep_k overwrites in-span)
    idbuf[token]  = -1;    // gap/default span id
  }
}

// ---------------- Kernel 2: per-span softmax -> per-token weights ----------------
// One wave per (b,k). Also zeroes this span's H row and writes sent —
// replaces the d_out memset dispatch (pool_k's atomics land on zeroed rows).
__global__ __launch_bounds__(64) void spanprep_k(
    const int* __restrict__ sps,
    const int* __restrict__ spe,
    const float* __restrict__ scores,
    float* __restrict__ wbuf,
    int* __restrict__ idbuf,
    float* __restrict__ Hout,
    float* __restrict__ sent) {
  const int bk = blockIdx.x;          // b*K + k
  const int b = bk >> 5;              // K = 32
  const int k = bk & 31;
  const int lane = threadIdx.x;

  // zero this span's output row (coalesced, 3 float4 iters)
  float4* hrow = (float4*)(Hout + (size_t)bk * DD);
  #pragma unroll
  for (int i = lane; i < DD / 4; i += 64) hrow[i] = make_float4(0.f, 0.f, 0.f, 0.f);

  int s0 = min(max(sps[bk], 0), LL);
  int e0 = min(max(spe[bk], 0), LL);

  const float* sc = scores + (size_t)b * LL;

  float m = NEGI;
  for (int l = s0 + lane; l < e0; l += 64) m = fmaxf(m, sc[l]);
  #pragma unroll
  for (int o = 32; o > 0; o >>= 1) m = fmaxf(m, __shfl_xor(m, o, 64));

  float ss = 0.f;
  for (int l = s0 + lane; l < e0; l += 64) {
    float v = sc[l];
    ss += (v > -1e29f) ? __expf(v - m) : 0.f;
  }
  #pragma unroll
  for (int o = 32; o > 0; o >>= 1) ss += __shfl_xor(ss, o, 64);

  const float inv = (ss > 0.f) ? (1.0f / ss) : 0.f;

  for (int l = s0 + lane; l < e0; l += 64) {
    float v = sc[l];
    wbuf[(size_t)b * LL + l] = (v > -1e29f) ? (__expf(v - m) * inv) : 0.f;
    idbuf[(size_t)b * LL + l] = k;   // spans are disjoint -> no write races
  }

  if (lane == 0) sent[bk] = (ss > 0.f) ? 1.0f : 0.0f;
}

// ---------------- Kernel 3: segmented weighted sum over fixed L-tiles ----------------
// grid (B, L/TILE, 3 chunks of 256 dims); block = 1 wave; lane owns 4 dims (float4).
// TILE=16 -> 6144 waves = 6 waves/SIMD for latency hiding.
__global__ __launch_bounds__(64) void pool_k(
    const float* __restrict__ th,
    const float* __restrict__ wbuf,
    const int* __restrict__ idbuf,
    float* __restrict__ Hout) {
  const int b = blockIdx.x;
  const int tile0 = blockIdx.y * TILE;
  const int chunk = blockIdx.z;
  const int lane = threadIdx.x;

  __shared__ float lw[TILE];
  __shared__ int lid[TILE];
  if (lane < TILE) {
    lw[lane]  = wbuf[(size_t)b * LL + tile0 + lane];
    lid[lane] = idbuf[(size_t)b * LL + tile0 + lane];
  }
  __syncthreads();

  const float4* base = (const float4*)(th + (size_t)b * LL * DD + chunk * 256) + lane;

  float4 acc = make_float4(0.f, 0.f, 0.f, 0.f);
  int cur = lid[0];

  #pragma unroll
  for (int t = 0; t < TILE; ++t) {
    const int id = lid[t];     // wave-uniform
    const float wt = lw[t];
    if (id != cur) {           // span boundary: flush accumulator
      if (cur >= 0) {
        float* o = Hout + ((size_t)(b * KK + cur) * DD) + chunk * 256 + (lane << 2);
        atomicAdd(o + 0, acc.x); atomicAdd(o + 1, acc.y);
        atomicAdd(o + 2, acc.z); atomicAdd(o + 3, acc.w);
      }
      acc = make_float4(0.f, 0.f, 0.f, 0.f);
      cur = id;
    }
    if (wt != 0.f) {           // skip gap/masked tokens (wave-uniform branch)
      float4 v = base[(size_t)(tile0 + t) * (DD / 4)];
      acc.x = fmaf(wt, v.x, acc.x);
      acc.y = fmaf(wt, v.y, acc.y);
      acc.z = fmaf(wt, v.z, acc.z);
      acc.w = fmaf(wt, v.w, acc.w);
    }
  }
  if (cur >= 0) {
    float* o = Hout + ((size_t)(b * KK + cur) * DD) + chunk * 256 + (lane << 2);
    atomicAdd(o + 0, acc.x); atomicAdd(o + 1, acc.y);
    atomicAdd(o + 2, acc.z); atomicAdd(o + 3, acc.w);
  }
}

extern "C" void kernel_launch(void* const* d_in, const int* in_sizes, int n_in,
                              void* d_out, int out_size, void* d_ws, size_t ws_size,
                              hipStream_t stream) {
  const float* th   = (const float*)d_in[0];  // [B,L,D] fp32
  const float* attn = (const float*)d_in[1];  // [B,L]   fp32
  const int*   sps  = (const int*)d_in[2];    // [B,K]
  const int*   spe  = (const int*)d_in[3];    // [B,K]
  const float* wp   = (const float*)d_in[4];  // [D]     fp32
  const float* bp   = (const float*)d_in[5];  // [1]     fp32

  float* Hout = (float*)d_out;                    // [B,K,D] then sent [B,K]
  float* sent = Hout + (size_t)BB * KK * DD;

  float* scores = (float*)d_ws;                   // B*L fp32   (128 KB)
  float* wbuf   = scores + (size_t)BB * LL;       // B*L fp32   (128 KB)
  int*   idbuf  = (int*)(wbuf + (size_t)BB * LL); // B*L int32  (128 KB)

  scores_k<<<dim3((BB * LL) / 4), dim3(256), 0, stream>>>(
      th, attn, wp, bp, scores, wbuf, idbuf);
  spanprep_k<<<dim3(BB * KK), dim3(64), 0, stream>>>(
      sps, spe, scores, wbuf, idbuf, Hout, sent);
  pool_k<<<dim3(BB, LL / TILE, 3), dim3(64), 0, stream>>>(th, wbuf, idbuf, Hout);
}

// Round 5
// 180.818 us; speedup vs baseline: 1.0699x; 1.0699x over previous
//
#include <hip/hip_runtime.h>

#define BB 16
#define LL 2048
#define DD 768
#define KK 32
#define TILE 32
#define NEGI -1e30f

// ---------------- Kernel 1: per-token scores + weight-buffer init ----------------
// One wave per token, fully coalesced: lane reads float4s {lane, lane+64, lane+128}
// of the 192-float4 row (each VMEM instruction = contiguous 1 KB).
__global__ __launch_bounds__(256) void scores_k(
    const float* __restrict__ th,
    const float* __restrict__ attn,
    const float* __restrict__ wp,
    const float* __restrict__ bp,
    float* __restrict__ scores,
    float* __restrict__ wbuf,
    int* __restrict__ idbuf) {
  const int lane = threadIdx.x & 63;
  const int wave = threadIdx.x >> 6;
  const int token = (blockIdx.x << 2) + wave;  // < B*L = 32768

  const float4* row = (const float4*)(th + (size_t)token * DD);
  const float4* wr  = (const float4*)wp;

  float4 a0 = row[lane], a1 = row[lane + 64], a2 = row[lane + 128];
  float4 w0 = wr[lane],  w1 = wr[lane + 64],  w2 = wr[lane + 128];

  float acc = 0.f;
  acc = fmaf(a0.x, w0.x, acc); acc = fmaf(a0.y, w0.y, acc);
  acc = fmaf(a0.z, w0.z, acc); acc = fmaf(a0.w, w0.w, acc);
  acc = fmaf(a1.x, w1.x, acc); acc = fmaf(a1.y, w1.y, acc);
  acc = fmaf(a1.z, w1.z, acc); acc = fmaf(a1.w, w1.w, acc);
  acc = fmaf(a2.x, w2.x, acc); acc = fmaf(a2.y, w2.y, acc);
  acc = fmaf(a2.z, w2.z, acc); acc = fmaf(a2.w, w2.w, acc);

  #pragma unroll
  for (int o = 32; o > 0; o >>= 1) acc += __shfl_xor(acc, o, 64);

  if (lane == 0) {
    float s = acc + bp[0];
    scores[token] = (attn[token] >= 0.5f) ? s : NEGI;
    wbuf[token]   = 0.f;   // gap/default weight (spanprep_k overwrites in-span)
    idbuf[token]  = -1;    // gap/default span id
  }
}

// ---------------- Kernel 2: per-span softmax -> per-token weights ----------------
// One wave per (b,k). Also zeroes this span's H row and writes sent —
// replaces the d_out memset dispatch (pool_k's atomics land on zeroed rows).
__global__ __launch_bounds__(64) void spanprep_k(
    const int* __restrict__ sps,
    const int* __restrict__ spe,
    const float* __restrict__ scores,
    float* __restrict__ wbuf,
    int* __restrict__ idbuf,
    float* __restrict__ Hout,
    float* __restrict__ sent) {
  const int bk = blockIdx.x;          // b*K + k
  const int b = bk >> 5;              // K = 32
  const int k = bk & 31;
  const int lane = threadIdx.x;

  // zero this span's output row (coalesced, 3 float4 iters)
  float4* hrow = (float4*)(Hout + (size_t)bk * DD);
  #pragma unroll
  for (int i = lane; i < DD / 4; i += 64) hrow[i] = make_float4(0.f, 0.f, 0.f, 0.f);

  int s0 = min(max(sps[bk], 0), LL);
  int e0 = min(max(spe[bk], 0), LL);

  const float* sc = scores + (size_t)b * LL;

  float m = NEGI;
  for (int l = s0 + lane; l < e0; l += 64) m = fmaxf(m, sc[l]);
  #pragma unroll
  for (int o = 32; o > 0; o >>= 1) m = fmaxf(m, __shfl_xor(m, o, 64));

  float ss = 0.f;
  for (int l = s0 + lane; l < e0; l += 64) {
    float v = sc[l];
    ss += (v > -1e29f) ? __expf(v - m) : 0.f;
  }
  #pragma unroll
  for (int o = 32; o > 0; o >>= 1) ss += __shfl_xor(ss, o, 64);

  const float inv = (ss > 0.f) ? (1.0f / ss) : 0.f;

  for (int l = s0 + lane; l < e0; l += 64) {
    float v = sc[l];
    wbuf[(size_t)b * LL + l] = (v > -1e29f) ? (__expf(v - m) * inv) : 0.f;
    idbuf[(size_t)b * LL + l] = k;   // spans are disjoint -> no write races
  }

  if (lane == 0) sent[bk] = (ss > 0.f) ? 1.0f : 0.0f;
}

// ---------------- Kernel 3: segmented weighted sum over fixed L-tiles ----------------
// grid (B, L/TILE, 3 chunks of 256 dims); block = 1 wave; lane owns 4 dims (float4).
// TILE=32 (16 regressed: 2x atomic flushes + half-granule streaming). Branchless
// inner loop: unconditional row load, FMA by wt (0 for gaps) -> 8 loads in flight.
__global__ __launch_bounds__(64) void pool_k(
    const float* __restrict__ th,
    const float* __restrict__ wbuf,
    const int* __restrict__ idbuf,
    float* __restrict__ Hout) {
  const int b = blockIdx.x;
  const int tile0 = blockIdx.y * TILE;
  const int chunk = blockIdx.z;
  const int lane = threadIdx.x;

  __shared__ float lw[TILE];
  __shared__ int lid[TILE];
  if (lane < TILE) {
    lw[lane]  = wbuf[(size_t)b * LL + tile0 + lane];
    lid[lane] = idbuf[(size_t)b * LL + tile0 + lane];
  }
  __syncthreads();

  const float4* base = (const float4*)(th + (size_t)b * LL * DD + chunk * 256) + lane;

  float4 acc = make_float4(0.f, 0.f, 0.f, 0.f);
  int cur = lid[0];

  #pragma unroll 8
  for (int t = 0; t < TILE; ++t) {
    const int id = lid[t];     // wave-uniform
    const float wt = lw[t];
    if (id != cur) {           // span boundary: flush accumulator (rare, uniform)
      if (cur >= 0) {
        float* o = Hout + ((size_t)(b * KK + cur) * DD) + chunk * 256 + (lane << 2);
        atomicAdd(o + 0, acc.x); atomicAdd(o + 1, acc.y);
        atomicAdd(o + 2, acc.z); atomicAdd(o + 3, acc.w);
      }
      acc = make_float4(0.f, 0.f, 0.f, 0.f);
      cur = id;
    }
    float4 v = base[(size_t)(tile0 + t) * (DD / 4)];  // unconditional: ILP
    acc.x = fmaf(wt, v.x, acc.x);
    acc.y = fmaf(wt, v.y, acc.y);
    acc.z = fmaf(wt, v.z, acc.z);
    acc.w = fmaf(wt, v.w, acc.w);
  }
  if (cur >= 0) {
    float* o = Hout + ((size_t)(b * KK + cur) * DD) + chunk * 256 + (lane << 2);
    atomicAdd(o + 0, acc.x); atomicAdd(o + 1, acc.y);
    atomicAdd(o + 2, acc.z); atomicAdd(o + 3, acc.w);
  }
}

extern "C" void kernel_launch(void* const* d_in, const int* in_sizes, int n_in,
                              void* d_out, int out_size, void* d_ws, size_t ws_size,
                              hipStream_t stream) {
  const float* th   = (const float*)d_in[0];  // [B,L,D] fp32
  const float* attn = (const float*)d_in[1];  // [B,L]   fp32
  const int*   sps  = (const int*)d_in[2];    // [B,K]
  const int*   spe  = (const int*)d_in[3];    // [B,K]
  const float* wp   = (const float*)d_in[4];  // [D]     fp32
  const float* bp   = (const float*)d_in[5];  // [1]     fp32

  float* Hout = (float*)d_out;                    // [B,K,D] then sent [B,K]
  float* sent = Hout + (size_t)BB * KK * DD;

  float* scores = (float*)d_ws;                   // B*L fp32   (128 KB)
  float* wbuf   = scores + (size_t)BB * LL;       // B*L fp32   (128 KB)
  int*   idbuf  = (int*)(wbuf + (size_t)BB * LL); // B*L int32  (128 KB)

  scores_k<<<dim3((BB * LL) / 4), dim3(256), 0, stream>>>(
      th, attn, wp, bp, scores, wbuf, idbuf);
  spanprep_k<<<dim3(BB * KK), dim3(64), 0, stream>>>(
      sps, spe, scores, wbuf, idbuf, Hout, sent);
  pool_k<<<dim3(BB, LL / TILE, 3), dim3(64), 0, stream>>>(th, wbuf, idbuf, Hout);
}

// Round 6
// 174.530 us; speedup vs baseline: 1.1084x; 1.0360x over previous
//
#include <hip/hip_runtime.h>

#define BB 16
#define LL 2048
#define DD 768
#define KK 32
#define NEGI -1e30f

// ---------------- Kernel 1: per-token scores ----------------
// One wave per token, fully coalesced: lane reads float4s {lane, lane+64, lane+128}
// of the 192-float4 row (each VMEM instruction = contiguous 1 KB).
__global__ __launch_bounds__(256) void scores_k(
    const float* __restrict__ th,
    const float* __restrict__ attn,
    const float* __restrict__ wp,
    const float* __restrict__ bp,
    float* __restrict__ scores) {
  const int lane = threadIdx.x & 63;
  const int wave = threadIdx.x >> 6;
  const int token = (blockIdx.x << 2) + wave;  // < B*L = 32768

  const float4* row = (const float4*)(th + (size_t)token * DD);
  const float4* wr  = (const float4*)wp;

  float4 a0 = row[lane], a1 = row[lane + 64], a2 = row[lane + 128];
  float4 w0 = wr[lane],  w1 = wr[lane + 64],  w2 = wr[lane + 128];

  float acc = 0.f;
  acc = fmaf(a0.x, w0.x, acc); acc = fmaf(a0.y, w0.y, acc);
  acc = fmaf(a0.z, w0.z, acc); acc = fmaf(a0.w, w0.w, acc);
  acc = fmaf(a1.x, w1.x, acc); acc = fmaf(a1.y, w1.y, acc);
  acc = fmaf(a1.z, w1.z, acc); acc = fmaf(a1.w, w1.w, acc);
  acc = fmaf(a2.x, w2.x, acc); acc = fmaf(a2.y, w2.y, acc);
  acc = fmaf(a2.z, w2.z, acc); acc = fmaf(a2.w, w2.w, acc);

  #pragma unroll
  for (int o = 32; o > 0; o >>= 1) acc += __shfl_xor(acc, o, 64);

  if (lane == 0) {
    float s = acc + bp[0];
    scores[token] = (attn[token] >= 0.5f) ? s : NEGI;
  }
}

// ---------------- Kernel 2: fused span softmax + gather-pool ----------------
// grid (B*K, 3 chunks of 256 dims); one wave per block.
// Recomputes span softmax stats from L2-hot scores (redundant x3 across chunks —
// VALU is idle anyway), stages normalized weights in LDS, then gathers the span's
// rows with direct float4 stores: no atomics, no H zeroing, no wbuf/idbuf.
__global__ __launch_bounds__(64) void pool2_k(
    const float* __restrict__ th,
    const float* __restrict__ scores,
    const int* __restrict__ sps,
    const int* __restrict__ spe,
    float* __restrict__ Hout,
    float* __restrict__ sent) {
  const int bk = blockIdx.x;          // b*K + k
  const int chunk = blockIdx.y;
  const int b = bk >> 5;              // K = 32
  const int lane = threadIdx.x;

  __shared__ float lw[LL];            // 8 KB: span length <= L

  int s0 = min(max(sps[bk], 0), LL);
  int e0 = min(max(spe[bk], 0), LL);

  const float* sc = scores + (size_t)b * LL;

  // span max
  float m = NEGI;
  for (int l = s0 + lane; l < e0; l += 64) m = fmaxf(m, sc[l]);
  #pragma unroll
  for (int o = 32; o > 0; o >>= 1) m = fmaxf(m, __shfl_xor(m, o, 64));

  // span exp-sum (guard: attn-masked tokens carry -1e30 and must contribute 0,
  // including the all-masked case where m == -1e30)
  float ss = 0.f;
  for (int l = s0 + lane; l < e0; l += 64) {
    float v = sc[l];
    ss += (v > -1e29f) ? __expf(v - m) : 0.f;
  }
  #pragma unroll
  for (int o = 32; o > 0; o >>= 1) ss += __shfl_xor(ss, o, 64);

  const float inv = (ss > 0.f) ? (1.0f / ss) : 0.f;

  // normalized weights -> LDS
  for (int l = s0 + lane; l < e0; l += 64) {
    float v = sc[l];
    lw[l - s0] = (v > -1e29f) ? (__expf(v - m) * inv) : 0.f;
  }
  __syncthreads();

  // gather-accumulate over span rows; lane owns 4 consecutive dims (16 B load)
  const float4* base = (const float4*)(th + (size_t)b * LL * DD + chunk * 256) + lane;
  float4 acc = make_float4(0.f, 0.f, 0.f, 0.f);
  #pragma unroll 8
  for (int l = s0; l < e0; ++l) {
    const float w = lw[l - s0];
    float4 t = base[(size_t)l * (DD / 4)];
    acc.x = fmaf(w, t.x, acc.x);
    acc.y = fmaf(w, t.y, acc.y);
    acc.z = fmaf(w, t.z, acc.z);
    acc.w = fmaf(w, t.w, acc.w);
  }

  // direct store (empty / all-masked spans store zeros — matches reference)
  float4* o = (float4*)(Hout + (size_t)bk * DD + chunk * 256) + lane;
  *o = acc;

  if (chunk == 0 && lane == 0) sent[bk] = (ss > 0.f) ? 1.0f : 0.0f;
}

extern "C" void kernel_launch(void* const* d_in, const int* in_sizes, int n_in,
                              void* d_out, int out_size, void* d_ws, size_t ws_size,
                              hipStream_t stream) {
  const float* th   = (const float*)d_in[0];  // [B,L,D] fp32
  const float* attn = (const float*)d_in[1];  // [B,L]   fp32
  const int*   sps  = (const int*)d_in[2];    // [B,K]
  const int*   spe  = (const int*)d_in[3];    // [B,K]
  const float* wp   = (const float*)d_in[4];  // [D]     fp32
  const float* bp   = (const float*)d_in[5];  // [1]     fp32

  float* Hout = (float*)d_out;                 // [B,K,D] then sent [B,K]
  float* sent = Hout + (size_t)BB * KK * DD;

  float* scores = (float*)d_ws;                // B*L fp32 (128 KB)

  scores_k<<<dim3((BB * LL) / 4), dim3(256), 0, stream>>>(th, attn, wp, bp, scores);
  pool2_k<<<dim3(BB * KK, 3), dim3(64), 0, stream>>>(th, scores, sps, spe, Hout, sent);
}